// Round 4
// baseline (339.405 us; speedup 1.0000x reference)
//
#include <hip/hip_runtime.h>
#include <stdint.h>

// Problem constants (B, LQ, LK, D fixed by the reference)
#define NB    32
#define SLQ   2048
#define SLK   2048
#define DD    128
#define QTILE 128          // q rows per workgroup (4 waves x 32)
#define KVB   64           // keys per block iteration
#define NKB   (SLK / KVB)  // 32

typedef __attribute__((ext_vector_type(8)))  short    bf16x8;
typedef __attribute__((ext_vector_type(16))) float    f32x16;
typedef __attribute__((ext_vector_type(4)))  float    f32x4v;
typedef __attribute__((ext_vector_type(4)))  uint32_t u32x4;
typedef __attribute__((ext_vector_type(2)))  uint32_t u32x2;

union FragU { uint32_t u[4]; bf16x8 v; };

// HW packed f32->bf16 (RNE), 1 inst per pair
__device__ __forceinline__ uint32_t cvtpk(float lo, float hi) {
    uint32_t r;
    asm("v_cvt_pk_bf16_f32 %0, %1, %2" : "=v"(r) : "v"(lo), "v"(hi));
    return r;
}
// a' = {lanes<32: a, lanes>=32: b[lane-32]}; b' = {lanes<32: a[lane+32], lanes>=32: b}
__device__ __forceinline__ void perm32swap(uint32_t& a, uint32_t& b) {
    asm("v_permlane32_swap_b32 %0, %1" : "+v"(a), "+v"(b));
}
// 16 mask bytes (0/1) -> 16 bits
__device__ __forceinline__ uint32_t pack16(u32x4 a) {
    uint32_t r0 = (((a.x & 0x01010101u) * 0x01020408u) >> 24) & 0xFu;
    uint32_t r1 = (((a.y & 0x01010101u) * 0x01020408u) >> 24) & 0xFu;
    uint32_t r2 = (((a.z & 0x01010101u) * 0x01020408u) >> 24) & 0xFu;
    uint32_t r3 = (((a.w & 0x01010101u) * 0x01020408u) >> 24) & 0xFu;
    return r0 | (r1 << 4) | (r2 << 8) | (r3 << 12);
}
#if __has_builtin(__builtin_amdgcn_exp2f)
#define EXP2(x) __builtin_amdgcn_exp2f(x)
#else
#define EXP2(x) exp2f(x)
#endif

__global__ __launch_bounds__(256, 2)
void attn_fwd(const float* __restrict__ qp, const float* __restrict__ kp,
              const float* __restrict__ vp, const void* __restrict__ mp,
              float* __restrict__ op)
{
    // Double-buffered LDS: 2x16KB K + 2x16KB V^T + 2x1KB mask bits = 66KB -> 2 blocks/CU
    __shared__ short    k_lds[2][KVB * DD];   // [64 key][128 d] bf16, 16B-XOR swizzle
    __shared__ short    vt_lds[2][DD * KVB];  // [128 d][64 key] bf16, 8B-XOR swizzle
    __shared__ uint32_t m_lds[2][QTILE * 2];  // [128 q][2] dwords of key-bits
    __shared__ int      det_flags;

    const int tid  = threadIdx.x;
    const int lane = tid & 63;
    const int wv   = tid >> 6;   // wave 0..3
    const int l31  = lane & 31;
    const int hi2  = lane >> 5;  // 0/1

    // XCD-chunked swizzle: 512 WGs, 8 XCDs -> each XCD gets 64 consecutive work ids
    const int bid = blockIdx.x;
    const int wg  = (bid & 7) * 64 + (bid >> 3);
    const int b   = wg >> 4;            // batch
    const int q0  = (wg & 15) * QTILE;  // q tile origin

    // ---- mask dtype self-detection (R2 FETCH proved u8; keep as safety) ----
    if (tid == 0) det_flags = 0;
    __syncthreads();
    {
        const u32x4 w = *(const u32x4*)((const char*)mp + tid * 16);
        const uint32_t any_hi    = (w.x | w.y | w.z | w.w) & 0xFFFFFF00u;
        const uint32_t any_mod84 = (w.y | w.w) & 0xFFu;
        const int f = (any_hi ? 1 : 0) | (any_mod84 ? 2 : 0);
        if (f) atomicOr(&det_flags, f);
    }
    __syncthreads();
    const int mflags = det_flags;
    const int mmode  = (mflags & 1) ? 0 : ((mflags & 2) ? 1 : 2);  // 0=u8, 1=i32, 2=i64

    // scale = log2(e)/sqrt(128): scores land in log2 units -> softmax is bare v_exp
    const float qsc = 0.12751744846458246f;

    // ---- persistent Q fragments (B-operand of swapped QK^T) ----
    bf16x8 qf[8];
    {
        const float* qrow = qp + ((size_t)b * SLQ + (size_t)(q0 + wv * 32 + l31)) * DD;
        #pragma unroll
        for (int ks = 0; ks < 8; ++ks) {
            f32x4v x0 = *(const f32x4v*)(qrow + 16 * ks + 8 * hi2);
            f32x4v x1 = *(const f32x4v*)(qrow + 16 * ks + 8 * hi2 + 4);
            FragU f;
            f.u[0] = cvtpk(x0.x * qsc, x0.y * qsc);
            f.u[1] = cvtpk(x0.z * qsc, x0.w * qsc);
            f.u[2] = cvtpk(x1.x * qsc, x1.y * qsc);
            f.u[3] = cvtpk(x1.z * qsc, x1.w * qsc);
            qf[ks] = f.v;
        }
    }

    f32x16 oacc[4];
    #pragma unroll
    for (int i = 0; i < 4; ++i)
        #pragma unroll
        for (int j = 0; j < 16; ++j) oacc[i][j] = 0.0f;
    float psum = 0.0f;

    const float* kb0 = kp + (size_t)b * SLK * DD;
    const float* vb0 = vp + (size_t)b * SLK * DD;
    const size_t mrow0 = ((size_t)b * SLQ + q0) * SLK;

    // ---- prefetch registers (T14: issue-early / write-late) ----
    f32x4v kreg[8];
    float  vreg[32];
    u32x4  mreg[2];

    const int vd  = tid & 127;   // d-row this thread stages for V^T
    const int vkh = tid >> 7;    // key half (0: keys 0-31, 1: keys 32-63)
    const int mqq = tid >> 1;    // mask q row
    const int mh  = tid & 1;     // mask key half
    const int swv = (vd & 15) << 3;  // V^T 8B-granular XOR

    #define LOAD_TILE(KB)                                                         \
        do {                                                                      \
            const int k0_ = (KB) * KVB;                                           \
            const float* kbase_ = kb0 + (size_t)k0_ * DD;                         \
            _Pragma("unroll")                                                     \
            for (int j = 0; j < 8; ++j)                                           \
                kreg[j] = *(const f32x4v*)(kbase_ + (j * 256 + tid) * 4);         \
            const float* vcol_ = vb0 + ((size_t)k0_ + 32 * vkh) * DD + vd;        \
            _Pragma("unroll")                                                     \
            for (int jj = 0; jj < 32; ++jj) vreg[jj] = vcol_[(size_t)jj * DD];    \
            if (mmode == 0) {                                                     \
                const uint8_t* ms_ = (const uint8_t*)mp + mrow0 +                 \
                                     (size_t)mqq * SLK + k0_ + mh * 32;           \
                mreg[0] = *(const u32x4*)(ms_);                                   \
                mreg[1] = *(const u32x4*)(ms_ + 16);                              \
            }                                                                     \
        } while (0)

    #define WRITE_LDS(BUF, KB)                                                    \
        do {                                                                      \
            short* kl_ = k_lds[(BUF)];                                            \
            short* vl_ = vt_lds[(BUF)];                                           \
            _Pragma("unroll")                                                     \
            for (int j = 0; j < 8; ++j) {                                         \
                const int flat = (j * 256 + tid) * 4;                             \
                const int kk   = flat >> 7;                                       \
                const int dd2  = (flat & 127) * 2;                                \
                u32x2 w2;                                                         \
                w2.x = cvtpk(kreg[j].x, kreg[j].y);                               \
                w2.y = cvtpk(kreg[j].z, kreg[j].w);                               \
                *(u32x2*)((char*)kl_ + kk * 256 + (dd2 ^ ((kk & 7) << 4))) = w2;  \
            }                                                                     \
            {                                                                     \
                char* vrow_ = (char*)vl_ + vd * 128;                              \
                _Pragma("unroll")                                                 \
                for (int j = 0; j < 8; ++j) {                                     \
                    u32x2 w2;                                                     \
                    w2.x = cvtpk(vreg[4 * j + 0], vreg[4 * j + 1]);               \
                    w2.y = cvtpk(vreg[4 * j + 2], vreg[4 * j + 3]);               \
                    *(u32x2*)(vrow_ + ((vkh * 64 + 8 * j) ^ swv)) = w2;           \
                }                                                                 \
            }                                                                     \
            if (mmode == 0) {                                                     \
                m_lds[(BUF)][mqq * 2 + mh] =                                      \
                    pack16(mreg[0]) | (pack16(mreg[1]) << 16);                    \
            } else {                                                              \
                const size_t e0_ = mrow0 + (size_t)mqq * SLK + (KB) * KVB + mh * 32; \
                uint32_t bits = 0;                                                \
                if (mmode == 1) {                                                 \
                    const uint32_t* s_ = (const uint32_t*)mp + e0_;               \
                    for (int j = 0; j < 32; ++j) bits |= (s_[j] ? 1u : 0u) << j;  \
                } else {                                                          \
                    const uint64_t* s_ = (const uint64_t*)mp + e0_;               \
                    for (int j = 0; j < 32; ++j) bits |= (s_[j] ? 1u : 0u) << j;  \
                }                                                                 \
                m_lds[(BUF)][mqq * 2 + mh] = bits;                                \
            }                                                                     \
        } while (0)

    // ---- prologue: stage tile 0 into buffer 0 ----
    LOAD_TILE(0);
    WRITE_LDS(0, 0);
    __syncthreads();

    for (int kb = 0; kb < NKB; ++kb) {
        const int cur = kb & 1;
        const short* kl = k_lds[cur];
        const short* vl = vt_lds[cur];

        // ---- issue next tile's global loads (fly during compute) ----
        if (kb + 1 < NKB) LOAD_TILE(kb + 1);

        // ---- swapped QK^T: sacc[t] = S^T (keys 32t.. x 32 q), log2 units ----
        f32x16 sacc[2];
        #pragma unroll
        for (int t = 0; t < 2; ++t)
            #pragma unroll
            for (int j = 0; j < 16; ++j) sacc[t][j] = 0.0f;
        __builtin_amdgcn_s_setprio(1);
        #pragma unroll
        for (int t = 0; t < 2; ++t) {
            const int row = 32 * t + l31;
            const char* krow = (const char*)kl + row * 256;
            const int sw = (row & 7) << 4;
            #pragma unroll
            for (int ks = 0; ks < 8; ++ks) {
                bf16x8 af = *(const bf16x8*)(krow + ((32 * ks + 16 * hi2) ^ sw));
                sacc[t] = __builtin_amdgcn_mfma_f32_32x32x16_bf16(af, qf[ks], sacc[t], 0, 0, 0);
            }
        }
        __builtin_amdgcn_s_setprio(0);

        // ---- softmax: p = exp2(s'), mask via bit tile, f32 row-sum, pack bf16 ----
        const u32x2 mq = *(const u32x2*)(&m_lds[cur][(32 * wv + l31) * 2]);
        uint32_t pw[2][8];
        #pragma unroll
        for (int t = 0; t < 2; ++t) {
            #pragma unroll
            for (int rr = 0; rr < 4; ++rr) {
                const uint32_t mn = ((t ? mq.y : mq.x) >> (8 * rr + 4 * hi2)) & 0xFu;
                float em[4];
                #pragma unroll
                for (int c = 0; c < 4; ++c) {
                    const float e = EXP2(sacc[t][4 * rr + c]);
                    em[c] = ((mn >> c) & 1u) ? 0.0f : e;
                }
                psum += (em[0] + em[1]) + (em[2] + em[3]);
                pw[t][2 * rr]     = cvtpk(em[0], em[1]);
                pw[t][2 * rr + 1] = cvtpk(em[2], em[3]);
            }
        }

        // ---- PV: O[32q x 128d] += P[32x64] * V[64x128] ----
        #pragma unroll
        for (int t = 0; t < 2; ++t) {
            #pragma unroll
            for (int kss = 0; kss < 2; ++kss) {
                uint32_t a0 = pw[t][4 * kss + 0], b0 = pw[t][4 * kss + 2];
                uint32_t a1 = pw[t][4 * kss + 1], b1 = pw[t][4 * kss + 3];
                perm32swap(a0, b0);
                perm32swap(a1, b1);
                FragU af;
                af.u[0] = a0; af.u[1] = a1; af.u[2] = b0; af.u[3] = b1;
                const int keyb = 64 * t + 32 * kss + 16 * hi2;
                __builtin_amdgcn_s_setprio(1);
                #pragma unroll
                for (int dt = 0; dt < 4; ++dt) {
                    const int drow = 32 * dt + l31;
                    const char* vrow = (const char*)vl + drow * 128;
                    const int sw8 = (drow & 15) << 3;
                    FragU vf;
                    *(u32x2*)&vf.u[0] = *(const u32x2*)(vrow + ((keyb)     ^ sw8));
                    *(u32x2*)&vf.u[2] = *(const u32x2*)(vrow + ((keyb + 8) ^ sw8));
                    oacc[dt] = __builtin_amdgcn_mfma_f32_32x32x16_bf16(af.v, vf.v, oacc[dt], 0, 0, 0);
                }
                __builtin_amdgcn_s_setprio(0);
            }
        }

        // ---- write next tile into the other buffer (vmcnt waits land here) ----
        if (kb + 1 < NKB) WRITE_LDS(cur ^ 1, kb + 1);
        __syncthreads();
    }

    // ---- epilogue: combine halves of row-sums, normalize, store fp32 ----
    psum += __shfl_xor(psum, 32);
    float* obase = op + ((size_t)b * SLQ + (size_t)(q0 + 32 * wv)) * DD + l31;
    #pragma unroll
    for (int r = 0; r < 16; ++r) {
        const int qrow = (r & 3) + 8 * (r >> 2) + 4 * hi2;
        const float s  = __shfl(psum, qrow);
        const float rs = 1.0f / s;
        #pragma unroll
        for (int dt = 0; dt < 4; ++dt) {
            obase[(size_t)qrow * DD + 32 * dt] = oacc[dt][r] * rs;
        }
    }
}

extern "C" void kernel_launch(void* const* d_in, const int* in_sizes, int n_in,
                              void* d_out, int out_size, void* d_ws, size_t ws_size,
                              hipStream_t stream)
{
    const float* q = (const float*)d_in[0];
    const float* k = (const float*)d_in[1];
    const float* v = (const float*)d_in[2];
    const void*  m = d_in[3];
    float*       o = (float*)d_out;
    hipLaunchKernelGGL(attn_fwd, dim3((NB * SLQ) / QTILE), dim3(256), 0, stream,
                       q, k, v, m, o);
}

// Round 5
// 205.206 us; speedup vs baseline: 1.6540x; 1.6540x over previous
//
#include <hip/hip_runtime.h>
#include <stdint.h>

// Problem constants (B, LQ, LK, D fixed by the reference)
#define NB    32
#define SLQ   2048
#define SLK   2048
#define DD    128
#define QTILE 128          // q rows per workgroup (4 waves x 32)
#define KVB   64           // keys per block iteration
#define NKB   (SLK / KVB)  // 32

typedef __attribute__((ext_vector_type(8)))  short    bf16x8;
typedef __attribute__((ext_vector_type(16))) float    f32x16;
typedef __attribute__((ext_vector_type(4)))  float    f32x4v;
typedef __attribute__((ext_vector_type(4)))  uint32_t u32x4;
typedef __attribute__((ext_vector_type(2)))  uint32_t u32x2;

union FragU { uint32_t u[4]; bf16x8 v; };

// HW packed f32->bf16 (RNE), 1 inst per pair
__device__ __forceinline__ uint32_t cvtpk(float lo, float hi) {
    uint32_t r;
    asm("v_cvt_pk_bf16_f32 %0, %1, %2" : "=v"(r) : "v"(lo), "v"(hi));
    return r;
}
// a' = {lanes<32: a, lanes>=32: b[lane-32]}; b' = {lanes<32: a[lane+32], lanes>=32: b}
__device__ __forceinline__ void perm32swap(uint32_t& a, uint32_t& b) {
    asm("v_permlane32_swap_b32 %0, %1" : "+v"(a), "+v"(b));
}
// 16 mask bytes (0/1) -> 16 bits
__device__ __forceinline__ uint32_t pack16(u32x4 a) {
    uint32_t r0 = (((a.x & 0x01010101u) * 0x01020408u) >> 24) & 0xFu;
    uint32_t r1 = (((a.y & 0x01010101u) * 0x01020408u) >> 24) & 0xFu;
    uint32_t r2 = (((a.z & 0x01010101u) * 0x01020408u) >> 24) & 0xFu;
    uint32_t r3 = (((a.w & 0x01010101u) * 0x01020408u) >> 24) & 0xFu;
    return r0 | (r1 << 4) | (r2 << 8) | (r3 << 12);
}
#if __has_builtin(__builtin_amdgcn_exp2f)
#define EXP2(x) __builtin_amdgcn_exp2f(x)
#else
#define EXP2(x) exp2f(x)
#endif

__global__ __launch_bounds__(256, 2)
void attn_fwd(const float* __restrict__ qp, const float* __restrict__ kp,
              const float* __restrict__ vp, const void* __restrict__ mp,
              float* __restrict__ op)
{
    // Single-buffer LDS (R3-proven schedule): 16KB K + 16KB V^T + 1KB mask bits
    __shared__ short    k_lds[KVB * DD];    // [64 key][128 d] bf16, 16B-XOR swizzle
    __shared__ short    vt_lds[DD * KVB];   // [128 d][64 key] bf16, 8B-XOR swizzle
    __shared__ uint32_t m_lds[QTILE * 2];   // [128 q][2] dwords of key-bits
    __shared__ int      det_flags;

    const int tid  = threadIdx.x;
    const int lane = tid & 63;
    const int wv   = tid >> 6;   // wave 0..3
    const int l31  = lane & 31;
    const int hi2  = lane >> 5;  // 0/1

    // XCD-chunked swizzle: 512 WGs, 8 XCDs -> each XCD gets 64 consecutive work ids
    const int bid = blockIdx.x;
    const int wg  = (bid & 7) * 64 + (bid >> 3);
    const int b   = wg >> 4;            // batch
    const int q0  = (wg & 15) * QTILE;  // q tile origin

    // ---- mask dtype self-detection (R2 FETCH proved u8; keep as safety) ----
    if (tid == 0) det_flags = 0;
    __syncthreads();
    {
        const u32x4 w = *(const u32x4*)((const char*)mp + tid * 16);
        const uint32_t any_hi    = (w.x | w.y | w.z | w.w) & 0xFFFFFF00u;
        const uint32_t any_mod84 = (w.y | w.w) & 0xFFu;
        const int f = (any_hi ? 1 : 0) | (any_mod84 ? 2 : 0);
        if (f) atomicOr(&det_flags, f);
    }
    __syncthreads();
    const int mflags = det_flags;
    const int mmode  = (mflags & 1) ? 0 : ((mflags & 2) ? 1 : 2);  // 0=u8, 1=i32, 2=i64

    // scale = log2(e)/sqrt(128): scores land in log2 units -> softmax is bare v_exp
    const float qsc = 0.12751744846458246f;

    // ---- persistent Q fragments (B-operand of swapped QK^T) ----
    bf16x8 qf[8];
    {
        const float* qrow = qp + ((size_t)b * SLQ + (size_t)(q0 + wv * 32 + l31)) * DD;
        #pragma unroll
        for (int ks = 0; ks < 8; ++ks) {
            f32x4v x0 = *(const f32x4v*)(qrow + 16 * ks + 8 * hi2);
            f32x4v x1 = *(const f32x4v*)(qrow + 16 * ks + 8 * hi2 + 4);
            FragU f;
            f.u[0] = cvtpk(x0.x * qsc, x0.y * qsc);
            f.u[1] = cvtpk(x0.z * qsc, x0.w * qsc);
            f.u[2] = cvtpk(x1.x * qsc, x1.y * qsc);
            f.u[3] = cvtpk(x1.z * qsc, x1.w * qsc);
            qf[ks] = f.v;
        }
    }

    f32x16 oacc[4];
    #pragma unroll
    for (int i = 0; i < 4; ++i)
        #pragma unroll
        for (int j = 0; j < 16; ++j) oacc[i][j] = 0.0f;
    float psum = 0.0f;

    const float* kb0 = kp + (size_t)b * SLK * DD;
    const float* vb0 = vp + (size_t)b * SLK * DD;
    const size_t mrow0 = ((size_t)b * SLQ + q0) * SLK;

    // ---- prefetch registers (T14: issue-early / write-late) ----
    f32x4v kreg[8];
    float  vreg[32];
    u32x4  mreg[2];

    const int vd  = tid & 127;       // d-row this thread stages for V^T
    const int vkh = tid >> 7;        // key half (0: keys 0-31, 1: keys 32-63)
    const int mqq = tid >> 1;        // mask q row
    const int mh  = tid & 1;         // mask key half
    const int swv = (vd & 15) << 3;  // V^T 8B-granular XOR

    #define LOAD_TILE(KB)                                                         \
        do {                                                                      \
            const int k0_ = (KB) * KVB;                                           \
            const float* kbase_ = kb0 + (size_t)k0_ * DD;                         \
            _Pragma("unroll")                                                     \
            for (int j = 0; j < 8; ++j)                                           \
                kreg[j] = *(const f32x4v*)(kbase_ + (j * 256 + tid) * 4);         \
            const float* vcol_ = vb0 + ((size_t)k0_ + 32 * vkh) * DD + vd;        \
            _Pragma("unroll")                                                     \
            for (int jj = 0; jj < 32; ++jj) vreg[jj] = vcol_[(size_t)jj * DD];    \
            if (mmode == 0) {                                                     \
                const uint8_t* ms_ = (const uint8_t*)mp + mrow0 +                 \
                                     (size_t)mqq * SLK + k0_ + mh * 32;           \
                mreg[0] = *(const u32x4*)(ms_);                                   \
                mreg[1] = *(const u32x4*)(ms_ + 16);                              \
            }                                                                     \
        } while (0)

    #define WRITE_LDS(KB)                                                         \
        do {                                                                      \
            _Pragma("unroll")                                                     \
            for (int j = 0; j < 8; ++j) {                                         \
                const int flat = (j * 256 + tid) * 4;                             \
                const int kk   = flat >> 7;                                       \
                const int dd2  = (flat & 127) * 2;                                \
                u32x2 w2;                                                         \
                w2.x = cvtpk(kreg[j].x, kreg[j].y);                               \
                w2.y = cvtpk(kreg[j].z, kreg[j].w);                               \
                *(u32x2*)((char*)k_lds + kk * 256 + (dd2 ^ ((kk & 7) << 4))) = w2;\
            }                                                                     \
            {                                                                     \
                char* vrow_ = (char*)vt_lds + vd * 128;                           \
                _Pragma("unroll")                                                 \
                for (int j = 0; j < 8; ++j) {                                     \
                    u32x2 w2;                                                     \
                    w2.x = cvtpk(vreg[4 * j + 0], vreg[4 * j + 1]);               \
                    w2.y = cvtpk(vreg[4 * j + 2], vreg[4 * j + 3]);               \
                    *(u32x2*)(vrow_ + ((vkh * 64 + 8 * j) ^ swv)) = w2;           \
                }                                                                 \
            }                                                                     \
            if (mmode == 0) {                                                     \
                m_lds[mqq * 2 + mh] = pack16(mreg[0]) | (pack16(mreg[1]) << 16);  \
            } else {                                                              \
                const size_t e0_ = mrow0 + (size_t)mqq * SLK + (KB) * KVB + mh * 32; \
                uint32_t bits = 0;                                                \
                if (mmode == 1) {                                                 \
                    const uint32_t* s_ = (const uint32_t*)mp + e0_;               \
                    for (int j = 0; j < 32; ++j) bits |= (s_[j] ? 1u : 0u) << j;  \
                } else {                                                          \
                    const uint64_t* s_ = (const uint64_t*)mp + e0_;               \
                    for (int j = 0; j < 32; ++j) bits |= (s_[j] ? 1u : 0u) << j;  \
                }                                                                 \
                m_lds[mqq * 2 + mh] = bits;                                       \
            }                                                                     \
        } while (0)

    LOAD_TILE(0);

    for (int kb = 0; kb < NKB; ++kb) {
        // ---- write LDS from prefetch regs; vmcnt wait lands HERE, pinned by
        //      the barrier structure (a full compute phase has hidden the loads)
        WRITE_LDS(kb);
        __syncthreads();

        // ---- issue next tile's loads, pinned above compute ----
        if (kb + 1 < NKB) LOAD_TILE(kb + 1);
        __builtin_amdgcn_sched_barrier(0);

        // ---- swapped QK^T: sacc[t] = S^T (keys 32t.. x 32 q), log2 units ----
        f32x16 sacc[2];
        #pragma unroll
        for (int t = 0; t < 2; ++t)
            #pragma unroll
            for (int j = 0; j < 16; ++j) sacc[t][j] = 0.0f;
        __builtin_amdgcn_s_setprio(1);
        #pragma unroll
        for (int t = 0; t < 2; ++t) {
            const int row = 32 * t + l31;
            const char* krow = (const char*)k_lds + row * 256;
            const int sw = (row & 7) << 4;
            #pragma unroll
            for (int ks = 0; ks < 8; ++ks) {
                bf16x8 af = *(const bf16x8*)(krow + ((32 * ks + 16 * hi2) ^ sw));
                sacc[t] = __builtin_amdgcn_mfma_f32_32x32x16_bf16(af, qf[ks], sacc[t], 0, 0, 0);
            }
        }
        __builtin_amdgcn_s_setprio(0);

        // ---- softmax: p = exp2(s'), mask via bit tile, f32 row-sum, pack bf16 ----
        const u32x2 mq = *(const u32x2*)(&m_lds[(32 * wv + l31) * 2]);
        uint32_t pw[2][8];
        #pragma unroll
        for (int t = 0; t < 2; ++t) {
            #pragma unroll
            for (int rr = 0; rr < 4; ++rr) {
                const uint32_t mn = ((t ? mq.y : mq.x) >> (8 * rr + 4 * hi2)) & 0xFu;
                float em[4];
                #pragma unroll
                for (int c = 0; c < 4; ++c) {
                    const float e = EXP2(sacc[t][4 * rr + c]);
                    em[c] = ((mn >> c) & 1u) ? 0.0f : e;
                }
                psum += (em[0] + em[1]) + (em[2] + em[3]);
                pw[t][2 * rr]     = cvtpk(em[0], em[1]);
                pw[t][2 * rr + 1] = cvtpk(em[2], em[3]);
            }
        }

        // ---- PV: O[32q x 128d] += P[32x64] * V[64x128] ----
        #pragma unroll
        for (int t = 0; t < 2; ++t) {
            #pragma unroll
            for (int kss = 0; kss < 2; ++kss) {
                uint32_t a0 = pw[t][4 * kss + 0], b0 = pw[t][4 * kss + 2];
                uint32_t a1 = pw[t][4 * kss + 1], b1 = pw[t][4 * kss + 3];
                perm32swap(a0, b0);
                perm32swap(a1, b1);
                FragU af;
                af.u[0] = a0; af.u[1] = a1; af.u[2] = b0; af.u[3] = b1;
                const int keyb = 64 * t + 32 * kss + 16 * hi2;
                __builtin_amdgcn_s_setprio(1);
                #pragma unroll
                for (int dt = 0; dt < 4; ++dt) {
                    const int drow = 32 * dt + l31;
                    const char* vrow = (const char*)vt_lds + drow * 128;
                    const int sw8 = (drow & 15) << 3;
                    FragU vf;
                    *(u32x2*)&vf.u[0] = *(const u32x2*)(vrow + ((keyb)     ^ sw8));
                    *(u32x2*)&vf.u[2] = *(const u32x2*)(vrow + ((keyb + 8) ^ sw8));
                    oacc[dt] = __builtin_amdgcn_mfma_f32_32x32x16_bf16(af.v, vf.v, oacc[dt], 0, 0, 0);
                }
                __builtin_amdgcn_s_setprio(0);
            }
        }
        __syncthreads();
    }

    // ---- epilogue: combine halves of row-sums, normalize, store fp32 ----
    psum += __shfl_xor(psum, 32);
    float* obase = op + ((size_t)b * SLQ + (size_t)(q0 + 32 * wv)) * DD + l31;
    #pragma unroll
    for (int r = 0; r < 16; ++r) {
        const int qrow = (r & 3) + 8 * (r >> 2) + 4 * hi2;
        const float s  = __shfl(psum, qrow);
        const float rs = 1.0f / s;
        #pragma unroll
        for (int dt = 0; dt < 4; ++dt) {
            obase[(size_t)qrow * DD + 32 * dt] = oacc[dt][r] * rs;
        }
    }
}

extern "C" void kernel_launch(void* const* d_in, const int* in_sizes, int n_in,
                              void* d_out, int out_size, void* d_ws, size_t ws_size,
                              hipStream_t stream)
{
    const float* q = (const float*)d_in[0];
    const float* k = (const float*)d_in[1];
    const float* v = (const float*)d_in[2];
    const void*  m = d_in[3];
    float*       o = (float*)d_out;
    hipLaunchKernelGGL(attn_fwd, dim3((NB * SLQ) / QTILE), dim3(256), 0, stream,
                       q, k, v, m, o);
}